// Round 2
// baseline (49350.281 us; speedup 1.0000x reference)
//
#include <hip/hip_runtime.h>
#include <cstdint>
#include <math.h>

#define U 896
#define HU 448
#define TU 2688
#define BB 8
#define TT 512
#define MM 80
#define CC 256

// ---------------- Threefry-2x32 (JAX-compatible) ----------------
__device__ __forceinline__ uint32_t rotl32(uint32_t v, int r){ return (v<<r)|(v>>(32-r)); }

__device__ void threefry(uint32_t k0, uint32_t k1, uint32_t x0, uint32_t x1,
                         uint32_t* o0, uint32_t* o1){
  uint32_t k2 = k0 ^ k1 ^ 0x1BD11BDAu;
  x0 += k0; x1 += k1;
  x0+=x1; x1=rotl32(x1,13); x1^=x0;
  x0+=x1; x1=rotl32(x1,15); x1^=x0;
  x0+=x1; x1=rotl32(x1,26); x1^=x0;
  x0+=x1; x1=rotl32(x1, 6); x1^=x0;
  x0+=k1; x1+=k2+1u;
  x0+=x1; x1=rotl32(x1,17); x1^=x0;
  x0+=x1; x1=rotl32(x1,29); x1^=x0;
  x0+=x1; x1=rotl32(x1,16); x1^=x0;
  x0+=x1; x1=rotl32(x1,24); x1^=x0;
  x0+=k2; x1+=k0+2u;
  x0+=x1; x1=rotl32(x1,13); x1^=x0;
  x0+=x1; x1=rotl32(x1,15); x1^=x0;
  x0+=x1; x1=rotl32(x1,26); x1^=x0;
  x0+=x1; x1=rotl32(x1, 6); x1^=x0;
  x0+=k0; x1+=k1+3u;
  x0+=x1; x1=rotl32(x1,17); x1^=x0;
  x0+=x1; x1=rotl32(x1,29); x1^=x0;
  x0+=x1; x1=rotl32(x1,16); x1^=x0;
  x0+=x1; x1=rotl32(x1,24); x1^=x0;
  x0+=k1; x1+=k2+4u;
  x0+=x1; x1=rotl32(x1,13); x1^=x0;
  x0+=x1; x1=rotl32(x1,15); x1^=x0;
  x0+=x1; x1=rotl32(x1,26); x1^=x0;
  x0+=x1; x1=rotl32(x1, 6); x1^=x0;
  x0+=k2; x1+=k0+5u;
  *o0 = x0; *o1 = x1;
}

// PARTITIONABLE threefry random_bits: element e of a flat draw under key
// (ka,kb): 64-bit iota counter -> (hi=0, lo=e); bits = o0 ^ o1.
__device__ float gumbel_from(uint32_t ka, uint32_t kb, uint32_t e){
  uint32_t o0, o1;
  threefry(ka, kb, 0u, e, &o0, &o1);
  uint32_t bits = o0 ^ o1;
  uint32_t m = bits >> 9;
  float u = (m == 0u) ? 1.17549435e-38f
                      : (__uint_as_float(m | 0x3f800000u) - 1.0f);
  float l1 = (float)log((double)u);
  float l2 = (float)log((double)(-l1));
  return -l2;
}

__device__ __forceinline__ float sig_f(float x){       // logistic
  return (float)(0.5 + 0.5*tanh(0.5*(double)x));
}
__device__ __forceinline__ float tanh_f(float x){ return (float)tanh((double)x); }

// ---------------- K0: per-step keys (partitionable / fold-like split) ----------------
// keys = split(key(42), 512):  key_t = threefry((0,42), 0, t) -> (o0,o1)
// kc,kf = split(key_t):        kc = threefry(key_t, 0, 0); kf = threefry(key_t, 0, 1)
__global__ __launch_bounds__(256) void k_keys(uint32_t* __restrict__ kc, uint32_t* __restrict__ kf){
  int t = blockIdx.x*256 + threadIdx.x;
  if (t >= TT) return;
  uint32_t ka, kb;
  threefry(0u, 42u, 0u, (uint32_t)t, &ka, &kb);
  uint32_t c0,c1,f0,f1;
  threefry(ka, kb, 0u, 0u, &c0, &c1);
  threefry(ka, kb, 0u, 1u, &f0, &f1);
  kc[2*t] = c0; kc[2*t+1] = c1;
  kf[2*t] = f0; kf[2*t+1] = f1;
}

// ---------------- K1: preactivations (x-part + recurrent part) ----------------
__global__ __launch_bounds__(256) void k_pre(
    const float* __restrict__ mels, const float* __restrict__ Wk,
    const float* __restrict__ Wr,  const float* __restrict__ bias,
    const float* __restrict__ hid, const float* __restrict__ cvs, const float* __restrict__ fvs,
    float* __restrict__ pre, float* __restrict__ ihb, int t)
{
  int g = blockIdx.x*256 + threadIdx.x;          // 0..21503
  int b = g / TU, col = g - b*TU;
  const float* h   = hid + b*U;
  const float* mel = mels + (b*TT + t)*MM;
  float x0=0.f,x1=0.f,x2=0.f,x3=0.f;
  #pragma unroll
  for (int m=0;m<MM;m+=4){
    x0 += mel[m  ]*Wk[(m  )*TU+col];
    x1 += mel[m+1]*Wk[(m+1)*TU+col];
    x2 += mel[m+2]*Wk[(m+2)*TU+col];
    x3 += mel[m+3]*Wk[(m+3)*TU+col];
  }
  float xacc = ((x0+x1)+(x2+x3));
  xacc += cvs[b]*Wk[80*TU+col];
  xacc += fvs[b]*Wk[81*TU+col];
  xacc += bias[col];                              // b[0]
  float i0=0.f,i1=0.f,i2=0.f,i3=0.f;
  for (int k=0;k<U;k+=4){
    i0 += h[k  ]*Wr[(k  )*TU+col];
    i1 += h[k+1]*Wr[(k+1)*TU+col];
    i2 += h[k+2]*Wr[(k+2)*TU+col];
    i3 += h[k+3]*Wr[(k+3)*TU+col];
  }
  float iacc = ((i0+i1)+(i2+i3)) + bias[TU+col];  // b[1]
  if (col < 2*U) pre[b*TU+col] = xacc + iacc;     // z,r merged
  else { pre[b*TU+col] = xacc; ihb[b*U + col - 2*U] = iacc; }  // h split
}

// ---------------- K2: coarse gates (first 448) + W1c ----------------
__global__ __launch_bounds__(448) void k_headc1(
    const float* __restrict__ pre, const float* __restrict__ ihb, const float* __restrict__ hid,
    const float* __restrict__ W1, const float* __restrict__ b1, float* __restrict__ hcb)
{
  __shared__ float sh[HU];
  int b = blockIdx.x, j = threadIdx.x;
  float az = pre[b*TU + j], ar = pre[b*TU + U + j], xh = pre[b*TU + 2*U + j];
  float z = sig_f(az), r = sig_f(ar);
  float hh = tanh_f(xh + r*ihb[b*U + j]);
  sh[j] = z*hid[b*U+j] + (1.0f - z)*hh;
  __syncthreads();
  float a0=0.f,a1=0.f,a2=0.f,a3=0.f;
  for (int i=0;i<HU;i+=4){
    a0 += sh[i  ]*W1[(i  )*HU+j];
    a1 += sh[i+1]*W1[(i+1)*HU+j];
    a2 += sh[i+2]*W1[(i+2)*HU+j];
    a3 += sh[i+3]*W1[(i+3)*HU+j];
  }
  hcb[b*HU+j] = fmaxf(((a0+a1)+(a2+a3)) + b1[j], 0.0f);
}

// ---------------- K4: fine head W1f from h1[:,448:] ----------------
__global__ __launch_bounds__(448) void k_headf1(
    const float* __restrict__ h1, const float* __restrict__ W1, const float* __restrict__ b1,
    float* __restrict__ hcb)
{
  __shared__ float sh[HU];
  int b = blockIdx.x, j = threadIdx.x;
  sh[j] = h1[b*U + HU + j];
  __syncthreads();
  float a0=0.f,a1=0.f,a2=0.f,a3=0.f;
  for (int i=0;i<HU;i+=4){
    a0 += sh[i  ]*W1[(i  )*HU+j];
    a1 += sh[i+1]*W1[(i+1)*HU+j];
    a2 += sh[i+2]*W1[(i+2)*HU+j];
    a3 += sh[i+3]*W1[(i+3)*HU+j];
  }
  hcb[b*HU+j] = fmaxf(((a0+a1)+(a2+a3)) + b1[j], 0.0f);
}

// ---------------- K3: coarse logits+softmax+gumbel+sample + fine gates -> h1 ----------------
__global__ __launch_bounds__(256) void k_samplec(
    const float* __restrict__ hcb, const float* __restrict__ W2, const float* __restrict__ b2,
    const uint32_t* __restrict__ kc,
    const float* __restrict__ pre, const float* __restrict__ ihb, const float* __restrict__ hid,
    const float* __restrict__ Wk,
    float* __restrict__ h1, float* __restrict__ cvs, int* __restrict__ nci, int t)
{
  int b = blockIdx.x, c = threadIdx.x;
  __shared__ float sh[HU];
  sh[c] = hcb[b*HU + c];
  if (c < HU-256) sh[256+c] = hcb[b*HU + 256 + c];
  __syncthreads();
  float a0=0.f,a1=0.f,a2=0.f,a3=0.f;
  for (int i=0;i<HU;i+=4){
    a0 += sh[i  ]*W2[(i  )*CC+c];
    a1 += sh[i+1]*W2[(i+1)*CC+c];
    a2 += sh[i+2]*W2[(i+2)*CC+c];
    a3 += sh[i+3]*W2[(i+3)*CC+c];
  }
  float logit = ((a0+a1)+(a2+a3)) + b2[c];
  __shared__ float red[256];
  red[c] = logit; __syncthreads();
  for (int s=128;s>0;s>>=1){ if (c<s) red[c] = fmaxf(red[c], red[c+s]); __syncthreads(); }
  float mx = red[0]; __syncthreads();
  float e = (float)exp((double)(logit - mx));
  red[c] = e; __syncthreads();
  for (int s=128;s>0;s>>=1){ if (c<s) red[c] = red[c] + red[c+s]; __syncthreads(); }
  float sum = red[0]; __syncthreads();
  float prob = e / sum;
  float v = prob + gumbel_from(kc[2*t], kc[2*t+1], (uint32_t)(b*CC + c));
  __shared__ int ridx[256];
  red[c] = v; ridx[c] = c; __syncthreads();
  for (int s=128;s>0;s>>=1){
    if (c<s){ float v2 = red[c+s]; int i2 = ridx[c+s];
      if (v2 > red[c]) { red[c]=v2; ridx[c]=i2; } }
    __syncthreads();
  }
  __shared__ float s_ncv;
  if (c==0){
    int nc = ridx[0]; nci[b] = nc;
    float val = (float)nc/255.0f*2.0f-1.0f;
    cvs[b] = val; s_ncv = val;
  }
  __syncthreads();
  float ncv = s_ncv;
  for (int u=c; u<U; u+=256){
    float az = pre[b*TU+u]      + ncv*Wk[82*TU+u];
    float ar = pre[b*TU+U+u]    + ncv*Wk[82*TU+U+u];
    float xh = pre[b*TU+2*U+u]  + ncv*Wk[82*TU+2*U+u];
    float z = sig_f(az), r = sig_f(ar);
    float hh = tanh_f(xh + r*ihb[b*U+u]);
    h1[b*U+u] = z*hid[b*U+u] + (1.0f-z)*hh;
  }
}

// ---------------- K5: fine logits+softmax+gumbel+sample + output ----------------
__global__ __launch_bounds__(256) void k_samplef(
    const float* __restrict__ hcb, const float* __restrict__ W2, const float* __restrict__ b2,
    const uint32_t* __restrict__ kf, const int* __restrict__ nci,
    float* __restrict__ fvs, float* __restrict__ out, int t)
{
  int b = blockIdx.x, c = threadIdx.x;
  __shared__ float sh[HU];
  sh[c] = hcb[b*HU + c];
  if (c < HU-256) sh[256+c] = hcb[b*HU + 256 + c];
  __syncthreads();
  float a0=0.f,a1=0.f,a2=0.f,a3=0.f;
  for (int i=0;i<HU;i+=4){
    a0 += sh[i  ]*W2[(i  )*CC+c];
    a1 += sh[i+1]*W2[(i+1)*CC+c];
    a2 += sh[i+2]*W2[(i+2)*CC+c];
    a3 += sh[i+3]*W2[(i+3)*CC+c];
  }
  float logit = ((a0+a1)+(a2+a3)) + b2[c];
  __shared__ float red[256];
  red[c] = logit; __syncthreads();
  for (int s=128;s>0;s>>=1){ if (c<s) red[c] = fmaxf(red[c], red[c+s]); __syncthreads(); }
  float mx = red[0]; __syncthreads();
  float e = (float)exp((double)(logit - mx));
  red[c] = e; __syncthreads();
  for (int s=128;s>0;s>>=1){ if (c<s) red[c] = red[c] + red[c+s]; __syncthreads(); }
  float sum = red[0]; __syncthreads();
  float prob = e / sum;
  float v = prob + gumbel_from(kf[2*t], kf[2*t+1], (uint32_t)(b*CC + c));
  __shared__ int ridx[256];
  red[c] = v; ridx[c] = c; __syncthreads();
  for (int s=128;s>0;s>>=1){
    if (c<s){ float v2 = red[c+s]; int i2 = ridx[c+s];
      if (v2 > red[c]) { red[c]=v2; ridx[c]=i2; } }
    __syncthreads();
  }
  if (c==0){
    int nf = ridx[0];
    float nff = (float)nf;
    fvs[b] = nff/255.0f*2.0f-1.0f;
    float ncf = (float)nci[b];
    out[b*TT + t] = (ncf*256.0f + nff)/32767.5f - 1.0f;
  }
}

extern "C" void kernel_launch(void* const* d_in, const int* in_sizes, int n_in,
                              void* d_out, int out_size, void* d_ws, size_t ws_size,
                              hipStream_t stream) {
  const float* mels = (const float*)d_in[0];
  const float* Wk   = (const float*)d_in[1];
  const float* Wr   = (const float*)d_in[2];
  const float* bias = (const float*)d_in[3];
  const float* W1c  = (const float*)d_in[4];
  const float* b1c  = (const float*)d_in[5];
  const float* W2c  = (const float*)d_in[6];
  const float* b2c  = (const float*)d_in[7];
  const float* W1f  = (const float*)d_in[8];
  const float* b1f  = (const float*)d_in[9];
  const float* W2f  = (const float*)d_in[10];
  const float* b2f  = (const float*)d_in[11];
  float* out = (float*)d_out;

  char* w = (char*)d_ws;
  uint32_t* kc = (uint32_t*)(w);
  uint32_t* kf = (uint32_t*)(w + 4096);
  float* hb   = (float*)(w + 8192);        // 2 * 8 * 896 floats
  float* pre  = (float*)(w + 65536);       // 8 * 2688
  float* ihb  = (float*)(w + 151552);      // 8 * 896
  float* hcb  = (float*)(w + 180224);      // 8 * 448
  float* cvs  = (float*)(w + 194560);      // 8
  float* fvs  = (float*)(w + 194592);      // 8
  int*   nci  = (int*)  (w + 194624);      // 8

  hipMemsetAsync(d_ws, 0, 194656, stream);
  k_keys<<<2,256,0,stream>>>(kc, kf);

  for (int t=0; t<TT; t++){
    float* hin  = hb + (t&1)*(BB*U);
    float* hout = hb + ((t+1)&1)*(BB*U);
    k_pre    <<<84,256,0,stream>>>(mels, Wk, Wr, bias, hin, cvs, fvs, pre, ihb, t);
    k_headc1 <<<8,448,0,stream>>>(pre, ihb, hin, W1c, b1c, hcb);
    k_samplec<<<8,256,0,stream>>>(hcb, W2c, b2c, kc, pre, ihb, hin, Wk, hout, cvs, nci, t);
    k_headf1 <<<8,448,0,stream>>>(hout, W1f, b1f, hcb);
    k_samplef<<<8,256,0,stream>>>(hcb, W2f, b2f, kf, nci, fvs, out, t);
  }
}

// Round 3
// 28942.764 us; speedup vs baseline: 1.7051x; 1.7051x over previous
//
#include <hip/hip_runtime.h>
#include <cstdint>
#include <math.h>

#define U 896
#define HU 448
#define TU 2688
#define BB 8
#define TT 512
#define MM 80
#define CC 256
#define MATB 84
#define HEADB 16
#define NBLK (MATB + HEADB)
#define NTH 512

// ---------------- Threefry-2x32 (JAX partitionable) ----------------
__device__ __forceinline__ uint32_t rotl32(uint32_t v, int r){ return (v<<r)|(v>>(32-r)); }

__device__ void threefry(uint32_t k0, uint32_t k1, uint32_t x0, uint32_t x1,
                         uint32_t* o0, uint32_t* o1){
  uint32_t k2 = k0 ^ k1 ^ 0x1BD11BDAu;
  x0 += k0; x1 += k1;
  x0+=x1; x1=rotl32(x1,13); x1^=x0;
  x0+=x1; x1=rotl32(x1,15); x1^=x0;
  x0+=x1; x1=rotl32(x1,26); x1^=x0;
  x0+=x1; x1=rotl32(x1, 6); x1^=x0;
  x0+=k1; x1+=k2+1u;
  x0+=x1; x1=rotl32(x1,17); x1^=x0;
  x0+=x1; x1=rotl32(x1,29); x1^=x0;
  x0+=x1; x1=rotl32(x1,16); x1^=x0;
  x0+=x1; x1=rotl32(x1,24); x1^=x0;
  x0+=k2; x1+=k0+2u;
  x0+=x1; x1=rotl32(x1,13); x1^=x0;
  x0+=x1; x1=rotl32(x1,15); x1^=x0;
  x0+=x1; x1=rotl32(x1,26); x1^=x0;
  x0+=x1; x1=rotl32(x1, 6); x1^=x0;
  x0+=k0; x1+=k1+3u;
  x0+=x1; x1=rotl32(x1,17); x1^=x0;
  x0+=x1; x1=rotl32(x1,29); x1^=x0;
  x0+=x1; x1=rotl32(x1,16); x1^=x0;
  x0+=x1; x1=rotl32(x1,24); x1^=x0;
  x0+=k1; x1+=k2+4u;
  x0+=x1; x1=rotl32(x1,13); x1^=x0;
  x0+=x1; x1=rotl32(x1,15); x1^=x0;
  x0+=x1; x1=rotl32(x1,26); x1^=x0;
  x0+=x1; x1=rotl32(x1, 6); x1^=x0;
  x0+=k2; x1+=k0+5u;
  *o0 = x0; *o1 = x1;
}

__device__ float gumbel_from(uint32_t ka, uint32_t kb, uint32_t e){
  uint32_t o0, o1;
  threefry(ka, kb, 0u, e, &o0, &o1);
  uint32_t bits = o0 ^ o1;
  uint32_t m = bits >> 9;
  float u = (m == 0u) ? 1.17549435e-38f
                      : (__uint_as_float(m | 0x3f800000u) - 1.0f);
  float l1 = (float)log((double)u);
  float l2 = (float)log((double)(-l1));
  return -l2;
}

__device__ __forceinline__ float sig_f(float x){
  return (float)(0.5 + 0.5*tanh(0.5*(double)x));
}
__device__ __forceinline__ float tanh_f(float x){ return (float)tanh((double)x); }

// ---------------- coherent (agent-scope, cache-bypassing) access helpers ----------------
__device__ __forceinline__ float gldf(const float* p){
  return __hip_atomic_load(p, __ATOMIC_RELAXED, __HIP_MEMORY_SCOPE_AGENT);
}
__device__ __forceinline__ void gstf(float* p, float v){
  __hip_atomic_store(p, v, __ATOMIC_RELAXED, __HIP_MEMORY_SCOPE_AGENT);
}
__device__ __forceinline__ int gldi(const int* p){
  return __hip_atomic_load(p, __ATOMIC_RELAXED, __HIP_MEMORY_SCOPE_AGENT);
}
__device__ __forceinline__ void gsti(int* p, int v){
  __hip_atomic_store(p, v, __ATOMIC_RELAXED, __HIP_MEMORY_SCOPE_AGENT);
}
__device__ __forceinline__ uint32_t fld(const uint32_t* p){
  return __hip_atomic_load(p, __ATOMIC_RELAXED, __HIP_MEMORY_SCOPE_AGENT);
}
__device__ __forceinline__ void spin_until(const uint32_t* p, uint32_t tgt){
  int n = 0;
  while (fld(p) < tgt){ if (++n > (1<<24)) break; }
}
__device__ __forceinline__ void arrive(uint32_t* p){
  __hip_atomic_fetch_add(p, 1u, __ATOMIC_RELEASE, __HIP_MEMORY_SCOPE_AGENT);
}

// ---------------- K0: per-step keys ----------------
__global__ __launch_bounds__(256) void k_keys(uint32_t* __restrict__ kc, uint32_t* __restrict__ kf){
  int t = blockIdx.x*256 + threadIdx.x;
  if (t >= TT) return;
  uint32_t ka, kb;
  threefry(0u, 42u, 0u, (uint32_t)t, &ka, &kb);
  uint32_t c0,c1,f0,f1;
  threefry(ka, kb, 0u, 0u, &c0, &c1);
  threefry(ka, kb, 0u, 1u, &f0, &f1);
  kc[2*t] = c0; kc[2*t+1] = c1;
  kf[2*t] = f0; kf[2*t+1] = f1;
}

// ---------------- persistent kernel ----------------
__global__ __launch_bounds__(NTH) void wavernn_persist(
    const float* __restrict__ mels, const float* __restrict__ Wk,
    const float* __restrict__ Wr,  const float* __restrict__ bias,
    const float* __restrict__ W1c, const float* __restrict__ b1c,
    const float* __restrict__ W2c, const float* __restrict__ b2c,
    const float* __restrict__ W1f, const float* __restrict__ b1f,
    const float* __restrict__ W2f, const float* __restrict__ b2f,
    float* __restrict__ out, char* __restrict__ ws)
{
  uint32_t* Fhv = (uint32_t*)(ws + 0);
  uint32_t* Fg  = (uint32_t*)(ws + 128);
  uint32_t* F1c = (uint32_t*)(ws + 256);
  uint32_t* Fncv= (uint32_t*)(ws + 384);
  uint32_t* Fh1 = (uint32_t*)(ws + 512);
  uint32_t* F1f = (uint32_t*)(ws + 640);
  uint32_t* Ffv = (uint32_t*)(ws + 768);
  const uint32_t* kc = (const uint32_t*)(ws + 1024);
  const uint32_t* kf = (const uint32_t*)(ws + 5120);
  float* ncvP0 = (float*)(ws + 9216);
  float* ncvP1 = (float*)(ws + 9248);
  float* fvs   = (float*)(ws + 9280);
  int*   nci   = (int*)  (ws + 9312);
  float* pre   = (float*)(ws + 9472);     // 8*2688
  float* ihb   = (float*)(ws + 95488);    // 8*896
  float* hgl   = (float*)(ws + 124160);   // 8*896
  float* h0c   = (float*)(ws + 152832);   // 8*448
  float* hcb   = (float*)(ws + 167168);   // 8*448

  __shared__ __align__(16) char smem[48000];

  const int bk = blockIdx.x, tid = threadIdx.x;

  if (bk < MATB) {
    // -------- mat block: big preactivation GEMM (P1) + fine gates/h1 (P5) --------
    float (*hl)[897]  = (float(*)[897])smem;            // 8*897*4 = 28704
    float (*mell)[84] = (float(*)[84])(smem + 28704);   // 2688 -> 31392
    float (*redW)[4]  = (float(*)[4]) (smem + 31392);   // 8192 -> 39584
    float (*redX)[4]  = (float(*)[4]) (smem + 39584);   // 8192 -> 47776

    const int col0 = bk*32;
    const int ks = tid>>6;
    const int r6 = tid&63;
    const int bb = r6>>3;
    const int col4 = col0 + (r6&7)*4;
    const int k0 = ks*112;
    const int m0 = ks*10;
    const int g5 = bk*512 + tid;
    const int u5 = g5 % 896;
    const int b5 = g5 / 896;

    for (int t=0; t<TT; ++t){
      // P1: wait h(t-1)
      if (tid==0 && t>0) spin_until(Fh1, 84u*(uint32_t)t);
      __syncthreads();
      for (int i=tid;i<7168;i+=NTH){ int bi=i/896, ki=i-bi*896; hl[bi][ki]=gldf(hgl+i); }
      for (int i=tid;i<640;i+=NTH){ int bi=i/80, mi=i-bi*80; mell[bi][mi]=mels[(bi*TT+t)*MM+mi]; }
      __syncthreads();
      float a0=0.f,a1=0.f,a2=0.f,a3=0.f;
      #pragma unroll 4
      for (int k=k0;k<k0+112;++k){
        const float4 w = *(const float4*)(Wr + (size_t)k*TU + col4);
        const float hv = hl[bb][k];
        a0 += w.x*hv; a1 += w.y*hv; a2 += w.z*hv; a3 += w.w*hv;
      }
      float x0=0.f,x1=0.f,x2=0.f,x3=0.f;
      #pragma unroll
      for (int m=m0;m<m0+10;++m){
        const float4 w = *(const float4*)(Wk + (size_t)m*TU + col4);
        const float mv = mell[bb][m];
        x0 += w.x*mv; x1 += w.y*mv; x2 += w.z*mv; x3 += w.w*mv;
      }
      redW[tid][0]=a0; redW[tid][1]=a1; redW[tid][2]=a2; redW[tid][3]=a3;
      redX[tid][0]=x0; redX[tid][1]=x1; redX[tid][2]=x2; redX[tid][3]=x3;
      __syncthreads();
      if (tid < 256){
        const int b2 = tid>>5, ci = tid&31;
        const int col = col0 + ci;
        const int base = b2*8 + (ci>>2), cc = ci&3;
        float sw=0.f, sx=0.f;
        #pragma unroll
        for (int s=0;s<8;++s){ sw += redW[s*64+base][cc]; sx += redX[s*64+base][cc]; }
        if (col < 1792) gstf(pre + b2*TU + col, sw + sx + bias[col] + bias[TU+col]);
        else { gstf(pre + b2*TU + col, sx + bias[col]);
               gstf(ihb + b2*896 + (col-1792), sw + bias[TU+col]); }
      }
      __syncthreads();
      if (tid==0) arrive(Fhv);

      // P5: fine gates -> h1 (blocks 0..13 cover all 7168 elements)
      if (bk < 14){
        if (tid==0) spin_until(Fncv, 8u*(uint32_t)(t+1));
        __syncthreads();
        const float* ncvNew = (t&1) ? ncvP1 : ncvP0;
        const float* ncvOld = (t&1) ? ncvP0 : ncvP1;
        {
          const float cvo = gldf(ncvOld+b5), fvo = gldf(fvs+b5), cvn = gldf(ncvNew+b5);
          float az = gldf(pre + b5*TU + u5)        + cvo*Wk[80*TU+u5]      + fvo*Wk[81*TU+u5]      + cvn*Wk[82*TU+u5];
          float ar = gldf(pre + b5*TU + 896 + u5)  + cvo*Wk[80*TU+896+u5]  + fvo*Wk[81*TU+896+u5]  + cvn*Wk[82*TU+896+u5];
          float ax = gldf(pre + b5*TU + 1792 + u5) + cvo*Wk[80*TU+1792+u5] + fvo*Wk[81*TU+1792+u5] + cvn*Wk[82*TU+1792+u5];
          float ih = gldf(ihb + b5*896 + u5);
          float z = sig_f(az), r = sig_f(ar);
          float hh = tanh_f(ax + r*ih);
          float hn = z*gldf(hgl + b5*896 + u5) + (1.0f - z)*hh;
          gstf(hgl + b5*896 + u5, hn);
        }
        __syncthreads();
      }
      if (tid==0) arrive(Fh1);
    }
  } else {
    // -------- head block: coarse gates (P2), head1 (P3/P6), sample (P4/P7) --------
    const int hb = bk - MATB;
    float* stg = (float*)smem;            // 3584 floats = 14336
    float* shh = (float*)(smem + 14336);  // 448 -> 16128
    float* red = (float*)(smem + 16128);  // 256 -> 17152
    int*  ridx = (int*)  (smem + 17152);  // 256 -> 18176

    const int o  = hb*224 + tid;          // valid when tid<224
    const int uo = o % 448;
    const int bo = o / 448;

    for (int t=0; t<TT; ++t){
      const float* ncvOld = (t&1) ? ncvP0 : ncvP1;
      float* ncvNew = (t&1) ? ncvP1 : ncvP0;

      // P2: coarse gates -> h0c
      if (tid==0){
        spin_until(Fhv, 84u*(uint32_t)(t+1));
        spin_until(Fncv, 8u*(uint32_t)t);
        spin_until(Ffv,  8u*(uint32_t)t);
      }
      __syncthreads();
      if (tid < 224){
        const float cv = gldf(ncvOld+bo), fv = gldf(fvs+bo);
        float az = gldf(pre + bo*TU + uo)        + cv*Wk[80*TU+uo]      + fv*Wk[81*TU+uo];
        float ar = gldf(pre + bo*TU + 896 + uo)  + cv*Wk[80*TU+896+uo]  + fv*Wk[81*TU+896+uo];
        float ax = gldf(pre + bo*TU + 1792 + uo) + cv*Wk[80*TU+1792+uo] + fv*Wk[81*TU+1792+uo];
        float ih = gldf(ihb + bo*896 + uo);
        float z = sig_f(az), r = sig_f(ar);
        float hh = tanh_f(ax + r*ih);
        gstf(h0c + bo*448 + uo, z*gldf(hgl + bo*896 + uo) + (1.0f - z)*hh);
      }
      __syncthreads();
      if (tid==0) arrive(Fg);

      // P3: head1c
      if (tid==0) spin_until(Fg, 16u*(uint32_t)(t+1));
      __syncthreads();
      for (int i=tid;i<3584;i+=NTH) stg[i] = gldf(h0c + i);
      __syncthreads();
      if (tid < 224){
        float a0=0.f,a1=0.f,a2=0.f,a3=0.f;
        const float* sb = stg + bo*448;
        #pragma unroll 4
        for (int i=0;i<448;i+=4){
          a0 += sb[i]  *W1c[(i)  *448+uo];
          a1 += sb[i+1]*W1c[(i+1)*448+uo];
          a2 += sb[i+2]*W1c[(i+2)*448+uo];
          a3 += sb[i+3]*W1c[(i+3)*448+uo];
        }
        gstf(hcb + bo*448 + uo, fmaxf(((a0+a1)+(a2+a3)) + b1c[uo], 0.0f));
      }
      __syncthreads();
      if (tid==0) arrive(F1c);

      // P4: coarse logits + softmax + gumbel + sample (blocks hb<8, b=hb)
      if (hb < 8){
        if (tid==0) spin_until(F1c, 16u*(uint32_t)(t+1));
        __syncthreads();
        for (int i=tid;i<448;i+=NTH) shh[i] = gldf(hcb + hb*448 + i);
        __syncthreads();
        float logit=0.f, ee=0.f;
        if (tid < 256){
          float a0=0.f,a1=0.f,a2=0.f,a3=0.f;
          #pragma unroll 4
          for (int i=0;i<448;i+=4){
            a0 += shh[i]  *W2c[(i)  *CC+tid];
            a1 += shh[i+1]*W2c[(i+1)*CC+tid];
            a2 += shh[i+2]*W2c[(i+2)*CC+tid];
            a3 += shh[i+3]*W2c[(i+3)*CC+tid];
          }
          logit = ((a0+a1)+(a2+a3)) + b2c[tid];
          red[tid] = logit;
        }
        __syncthreads();
        for (int s=128;s>0;s>>=1){ if (tid<s) red[tid]=fmaxf(red[tid],red[tid+s]); __syncthreads(); }
        float mx = red[0]; __syncthreads();
        if (tid < 256){ ee = (float)exp((double)(logit-mx)); red[tid]=ee; }
        __syncthreads();
        for (int s=128;s>0;s>>=1){ if (tid<s) red[tid]+=red[tid+s]; __syncthreads(); }
        float sum = red[0]; __syncthreads();
        if (tid < 256){
          float v = ee/sum + gumbel_from(kc[2*t], kc[2*t+1], (uint32_t)(hb*CC + tid));
          red[tid]=v; ridx[tid]=tid;
        }
        __syncthreads();
        for (int s=128;s>0;s>>=1){
          if (tid<s){ if (red[tid+s]>red[tid]){ red[tid]=red[tid+s]; ridx[tid]=ridx[tid+s]; } }
          __syncthreads();
        }
        if (tid==0){
          int nc = ridx[0];
          gsti(nci + hb, nc);
          gstf(ncvNew + hb, (float)nc/255.0f*2.0f - 1.0f);
          arrive(Fncv);
        }
      }

      // P6: head1f (needs h1)
      if (tid==0) spin_until(Fh1, 84u*(uint32_t)(t+1));
      __syncthreads();
      for (int i=tid;i<3584;i+=NTH){ int bi=i/448, ui=i-bi*448; stg[i] = gldf(hgl + bi*896 + 448 + ui); }
      __syncthreads();
      if (tid < 224){
        float a0=0.f,a1=0.f,a2=0.f,a3=0.f;
        const float* sb = stg + bo*448;
        #pragma unroll 4
        for (int i=0;i<448;i+=4){
          a0 += sb[i]  *W1f[(i)  *448+uo];
          a1 += sb[i+1]*W1f[(i+1)*448+uo];
          a2 += sb[i+2]*W1f[(i+2)*448+uo];
          a3 += sb[i+3]*W1f[(i+3)*448+uo];
        }
        gstf(hcb + bo*448 + uo, fmaxf(((a0+a1)+(a2+a3)) + b1f[uo], 0.0f));
      }
      __syncthreads();
      if (tid==0) arrive(F1f);

      // P7: fine logits + sample + output (blocks hb<8)
      if (hb < 8){
        if (tid==0) spin_until(F1f, 16u*(uint32_t)(t+1));
        __syncthreads();
        for (int i=tid;i<448;i+=NTH) shh[i] = gldf(hcb + hb*448 + i);
        __syncthreads();
        float logit=0.f, ee=0.f;
        if (tid < 256){
          float a0=0.f,a1=0.f,a2=0.f,a3=0.f;
          #pragma unroll 4
          for (int i=0;i<448;i+=4){
            a0 += shh[i]  *W2f[(i)  *CC+tid];
            a1 += shh[i+1]*W2f[(i+1)*CC+tid];
            a2 += shh[i+2]*W2f[(i+2)*CC+tid];
            a3 += shh[i+3]*W2f[(i+3)*CC+tid];
          }
          logit = ((a0+a1)+(a2+a3)) + b2f[tid];
          red[tid] = logit;
        }
        __syncthreads();
        for (int s=128;s>0;s>>=1){ if (tid<s) red[tid]=fmaxf(red[tid],red[tid+s]); __syncthreads(); }
        float mx = red[0]; __syncthreads();
        if (tid < 256){ ee = (float)exp((double)(logit-mx)); red[tid]=ee; }
        __syncthreads();
        for (int s=128;s>0;s>>=1){ if (tid<s) red[tid]+=red[tid+s]; __syncthreads(); }
        float sum = red[0]; __syncthreads();
        if (tid < 256){
          float v = ee/sum + gumbel_from(kf[2*t], kf[2*t+1], (uint32_t)(hb*CC + tid));
          red[tid]=v; ridx[tid]=tid;
        }
        __syncthreads();
        for (int s=128;s>0;s>>=1){
          if (tid<s){ if (red[tid+s]>red[tid]){ red[tid]=red[tid+s]; ridx[tid]=ridx[tid+s]; } }
          __syncthreads();
        }
        if (tid==0){
          int nf = ridx[0];
          gstf(fvs + hb, (float)nf/255.0f*2.0f - 1.0f);
          int nc = gldi(nci + hb);
          out[hb*TT + t] = ((float)nc*256.0f + (float)nf)/32767.5f - 1.0f;
          arrive(Ffv);
        }
      }
    }
  }
}

extern "C" void kernel_launch(void* const* d_in, const int* in_sizes, int n_in,
                              void* d_out, int out_size, void* d_ws, size_t ws_size,
                              hipStream_t stream) {
  const float* mels = (const float*)d_in[0];
  const float* Wk   = (const float*)d_in[1];
  const float* Wr   = (const float*)d_in[2];
  const float* bias = (const float*)d_in[3];
  const float* W1c  = (const float*)d_in[4];
  const float* b1c  = (const float*)d_in[5];
  const float* W2c  = (const float*)d_in[6];
  const float* b2c  = (const float*)d_in[7];
  const float* W1f  = (const float*)d_in[8];
  const float* b1f  = (const float*)d_in[9];
  const float* W2f  = (const float*)d_in[10];
  const float* b2f  = (const float*)d_in[11];
  float* out = (float*)d_out;
  char* wsb = (char*)d_ws;

  uint32_t* kc = (uint32_t*)(wsb + 1024);
  uint32_t* kf = (uint32_t*)(wsb + 5120);

  hipMemsetAsync(d_ws, 0, 181504, stream);
  k_keys<<<2,256,0,stream>>>(kc, kf);

  void* args[] = { (void*)&mels, (void*)&Wk, (void*)&Wr, (void*)&bias,
                   (void*)&W1c, (void*)&b1c, (void*)&W2c, (void*)&b2c,
                   (void*)&W1f, (void*)&b1f, (void*)&W2f, (void*)&b2f,
                   (void*)&out, (void*)&wsb };
  hipLaunchCooperativeKernel((const void*)wavernn_persist, dim3(NBLK), dim3(NTH),
                             args, 0, stream);
}

// Round 4
// 25242.966 us; speedup vs baseline: 1.9550x; 1.1466x over previous
//
#include <hip/hip_runtime.h>
#include <cstdint>
#include <math.h>

#define U 896
#define HU 448
#define TU 2688
#define BB 8
#define TT 512
#define MM 80
#define CC 256
#define NTH 512
#define NBLK 164

// ---------------- Threefry-2x32 (JAX partitionable) ----------------
__device__ __forceinline__ uint32_t rotl32(uint32_t v, int r){ return (v<<r)|(v>>(32-r)); }

__device__ void threefry(uint32_t k0, uint32_t k1, uint32_t x0, uint32_t x1,
                         uint32_t* o0, uint32_t* o1){
  uint32_t k2 = k0 ^ k1 ^ 0x1BD11BDAu;
  x0 += k0; x1 += k1;
  x0+=x1; x1=rotl32(x1,13); x1^=x0;
  x0+=x1; x1=rotl32(x1,15); x1^=x0;
  x0+=x1; x1=rotl32(x1,26); x1^=x0;
  x0+=x1; x1=rotl32(x1, 6); x1^=x0;
  x0+=k1; x1+=k2+1u;
  x0+=x1; x1=rotl32(x1,17); x1^=x0;
  x0+=x1; x1=rotl32(x1,29); x1^=x0;
  x0+=x1; x1=rotl32(x1,16); x1^=x0;
  x0+=x1; x1=rotl32(x1,24); x1^=x0;
  x0+=k2; x1+=k0+2u;
  x0+=x1; x1=rotl32(x1,13); x1^=x0;
  x0+=x1; x1=rotl32(x1,15); x1^=x0;
  x0+=x1; x1=rotl32(x1,26); x1^=x0;
  x0+=x1; x1=rotl32(x1, 6); x1^=x0;
  x0+=k0; x1+=k1+3u;
  x0+=x1; x1=rotl32(x1,17); x1^=x0;
  x0+=x1; x1=rotl32(x1,29); x1^=x0;
  x0+=x1; x1=rotl32(x1,16); x1^=x0;
  x0+=x1; x1=rotl32(x1,24); x1^=x0;
  x0+=k1; x1+=k2+4u;
  x0+=x1; x1=rotl32(x1,13); x1^=x0;
  x0+=x1; x1=rotl32(x1,15); x1^=x0;
  x0+=x1; x1=rotl32(x1,26); x1^=x0;
  x0+=x1; x1=rotl32(x1, 6); x1^=x0;
  x0+=k2; x1+=k0+5u;
  *o0 = x0; *o1 = x1;
}

__device__ float gumbel_from(uint32_t ka, uint32_t kb, uint32_t e){
  uint32_t o0, o1;
  threefry(ka, kb, 0u, e, &o0, &o1);
  uint32_t bits = o0 ^ o1;
  uint32_t m = bits >> 9;
  float u = (m == 0u) ? 1.17549435e-38f
                      : (__uint_as_float(m | 0x3f800000u) - 1.0f);
  float l1 = (float)log((double)u);
  float l2 = (float)log((double)(-l1));
  return -l2;
}

__device__ __forceinline__ float sig_f(float x){
  return (float)(0.5 + 0.5*tanh(0.5*(double)x));
}
__device__ __forceinline__ float tanh_f(float x){ return (float)tanh((double)x); }

// ---------------- coherent (agent-scope, cache-bypassing) access ----------------
__device__ __forceinline__ float gldf(const float* p){
  return __hip_atomic_load(p, __ATOMIC_RELAXED, __HIP_MEMORY_SCOPE_AGENT);
}
__device__ __forceinline__ void gstf(float* p, float v){
  __hip_atomic_store(p, v, __ATOMIC_RELAXED, __HIP_MEMORY_SCOPE_AGENT);
}
__device__ __forceinline__ int gldi(const int* p){
  return __hip_atomic_load(p, __ATOMIC_RELAXED, __HIP_MEMORY_SCOPE_AGENT);
}
__device__ __forceinline__ void gsti(int* p, int v){
  __hip_atomic_store(p, v, __ATOMIC_RELAXED, __HIP_MEMORY_SCOPE_AGENT);
}
__device__ __forceinline__ uint32_t fld(const uint32_t* p){
  return __hip_atomic_load(p, __ATOMIC_RELAXED, __HIP_MEMORY_SCOPE_AGENT);
}
__device__ __forceinline__ void spin_until(const uint32_t* p, uint32_t tgt){
  int n = 0;
  while (fld(p) < tgt){ __builtin_amdgcn_s_sleep(1); if (++n > (1<<20)) break; }
}
__device__ __forceinline__ void arrive(uint32_t* p){
  __hip_atomic_fetch_add(p, 1u, __ATOMIC_RELEASE, __HIP_MEMORY_SCOPE_AGENT);
}

__device__ __forceinline__ void fma4(float4& a, const float4& w, float h){
  a.x += w.x*h; a.y += w.y*h; a.z += w.z*h; a.w += w.w*h;
}

// ---------------- K0: per-step keys ----------------
__global__ __launch_bounds__(256) void k_keys(uint32_t* __restrict__ kc, uint32_t* __restrict__ kf){
  int t = blockIdx.x*256 + threadIdx.x;
  if (t >= TT) return;
  uint32_t ka, kb;
  threefry(0u, 42u, 0u, (uint32_t)t, &ka, &kb);
  uint32_t c0,c1,f0,f1;
  threefry(ka, kb, 0u, 0u, &c0, &c1);
  threefry(ka, kb, 0u, 1u, &f0, &f1);
  kc[2*t] = c0; kc[2*t+1] = c1;
  kf[2*t] = f0; kf[2*t+1] = f1;
}

// softmax + gumbel + argmax over 256 classes (bit-identical trees to round 2)
__device__ __forceinline__ int do_sample(char* smem, int tid, const float* lgt, int b,
                                         uint32_t ka, uint32_t kb){
  float* redS = (float*)smem;
  int* ridxS = (int*)(smem + 1024);
  float logit = 0.f, ee = 0.f;
  if (tid < 256){ logit = gldf(lgt + b*CC + tid); redS[tid] = logit; }
  __syncthreads();
  for (int s=128;s>0;s>>=1){ if (tid<s) redS[tid] = fmaxf(redS[tid], redS[tid+s]); __syncthreads(); }
  float mx = redS[0]; __syncthreads();
  if (tid < 256){ ee = (float)exp((double)(logit - mx)); redS[tid] = ee; }
  __syncthreads();
  for (int s=128;s>0;s>>=1){ if (tid<s) redS[tid] += redS[tid+s]; __syncthreads(); }
  float sum = redS[0]; __syncthreads();
  if (tid < 256){
    float v = ee/sum + gumbel_from(ka, kb, (uint32_t)(b*CC + tid));
    redS[tid] = v; ridxS[tid] = tid;
  }
  __syncthreads();
  for (int s=128;s>0;s>>=1){
    if (tid<s){ if (redS[tid+s] > redS[tid]){ redS[tid]=redS[tid+s]; ridxS[tid]=ridxS[tid+s]; } }
    __syncthreads();
  }
  int r = ridxS[0];
  __syncthreads();
  return r;
}

// ---------------- persistent kernel ----------------
__global__ __launch_bounds__(NTH, 2) void wavernn_persist(
    const float* __restrict__ mels, const float* __restrict__ Wk,
    const float* __restrict__ Wr,  const float* __restrict__ bias,
    const float* __restrict__ W1c, const float* __restrict__ b1c,
    const float* __restrict__ W2c, const float* __restrict__ b2c,
    const float* __restrict__ W1f, const float* __restrict__ b1f,
    const float* __restrict__ W2f, const float* __restrict__ b2f,
    float* __restrict__ out, char* __restrict__ ws)
{
  uint32_t* Fhv = (uint32_t*)(ws + 0);
  uint32_t* Fg  = (uint32_t*)(ws + 128);
  uint32_t* F1c = (uint32_t*)(ws + 256);
  uint32_t* F2c = (uint32_t*)(ws + 384);
  uint32_t* Fh1 = (uint32_t*)(ws + 512);
  uint32_t* F1f = (uint32_t*)(ws + 640);
  uint32_t* F2f = (uint32_t*)(ws + 768);
  uint32_t* Ffv = (uint32_t*)(ws + 896);
  const uint32_t* kc = (const uint32_t*)(ws + 1024);
  const uint32_t* kf = (const uint32_t*)(ws + 5120);
  float* ncvB = (float*)(ws + 9216);   // [2][8]
  float* fvsB = (float*)(ws + 9280);   // [2][8]
  int*   nci  = (int*)  (ws + 9344);   // [8]
  float* pre  = (float*)(ws + 9472);   // 8*2688
  float* ihb  = (float*)(ws + 95488);  // 8*896
  float* hgl  = (float*)(ws + 124160); // [2][8*896]
  float* h0c  = (float*)(ws + 181504); // 8*448
  float* hcbC = (float*)(ws + 195840); // 8*448
  float* hcbF = (float*)(ws + 210176); // 8*448
  float* lgtC = (float*)(ws + 224512); // 8*256
  float* lgtF = (float*)(ws + 232704); // 8*256

  __shared__ __align__(16) char smem[40960];
  const int bk = blockIdx.x, tid = threadIdx.x;

  if (bk < 84){
    // ======== coarse pool: GEMM (all), gates(76-83), h1c(0-55), h2c(56-71), sample_c(0-7) ========
    const int c4i = tid & 7, ks = tid >> 3;        // ks 0..63
    const int cb = bk*32 + c4i*4;
    const int k0 = ks*14;
    const bool zr = (bk < 56);                     // cols < 1792
    float* hlf = (float*)smem;                     // [8][1024]
    float (*red)[20] = (float(*)[20])smem;         // aliased after h-regs loaded

    for (int t=0; t<TT; ++t){
      // ---- GEMM: pre = [h;mel;cv]·[Wr;Wk] (+bias); fv/ncv corrections deferred ----
      if (tid==0) spin_until(Fh1, 8u*(uint32_t)t);
      __syncthreads();
      const int hs = (t&1)*7168;
      for (int i=tid;i<8192;i+=NTH){
        int b = i>>10, k = i&1023;
        float v;
        if (k < 896) v = gldf(hgl + hs + b*896 + k);
        else if (k < 976) v = mels[((size_t)b*TT + t)*MM + (k-896)];
        else if (k == 976) v = gldf(ncvB + ((t+1)&1)*8 + b);
        else v = 0.f;
        hlf[i] = v;
      }
      __syncthreads();
      float hrW[8][14]; float hrX0[8], hrX1[8];
      #pragma unroll
      for (int b=0;b<8;++b){
        #pragma unroll
        for (int q=0;q<7;++q){
          float2 h2 = *(float2*)&hlf[b*1024 + k0 + 2*q];
          hrW[b][2*q] = h2.x; hrW[b][2*q+1] = h2.y;
        }
        float2 h2 = *(float2*)&hlf[b*1024 + 896 + ks*2];
        hrX0[b] = h2.x; hrX1[b] = h2.y;
      }
      __syncthreads();
      float4 accW[8], accX[8];
      #pragma unroll
      for (int b=0;b<8;++b){ accW[b] = make_float4(0,0,0,0); accX[b] = make_float4(0,0,0,0); }
      #pragma unroll
      for (int jj=0;jj<14;++jj){
        const float4 w = *(const float4*)(Wr + (size_t)(k0+jj)*TU + cb);
        #pragma unroll
        for (int b=0;b<8;++b) fma4(accW[b], w, hrW[b][jj]);
      }
      {
        const int xk = 896 + ks*2;
        const int r0 = ((xk   < 978) ? xk   : 978) - 896;   // rows 80..82 exist in Wk
        const int r1 = ((xk+1 < 978) ? xk+1 : 978) - 896;
        const float4 w0 = *(const float4*)(Wk + (size_t)r0*TU + cb);
        const float4 w1 = *(const float4*)(Wk + (size_t)r1*TU + cb);
        #pragma unroll
        for (int b=0;b<8;++b){ fma4(accX[b], w0, hrX0[b]); fma4(accX[b], w1, hrX1[b]); }
      }
      if (zr){
        #pragma unroll
        for (int b=0;b<8;++b){
          accW[b].x += accX[b].x; accW[b].y += accX[b].y;
          accW[b].z += accX[b].z; accW[b].w += accX[b].w;
        }
      }
      // reduce passes (static indexing only)
      #define STORE4(A0,A1,A2,A3) \
        *(float4*)&red[tid][0]  = (A0); *(float4*)&red[tid][4]  = (A1); \
        *(float4*)&red[tid][8]  = (A2); *(float4*)&red[tid][12] = (A3);
      #define REDOUT(BBASE, MODE) \
        if (tid < 128){ \
          const int ci = tid & 31, bp = tid >> 5; \
          float s = 0.f; \
          _Pragma("unroll 8") \
          for (int q=0;q<64;++q) s += red[q*8 + (ci>>2)][bp*4 + (ci&3)]; \
          const int col = bk*32 + ci; \
          const int b = (BBASE) + bp; \
          if ((MODE)==0) gstf(pre + b*TU + col, s + bias[col] + bias[TU+col]); \
          else if ((MODE)==1) gstf(ihb + b*896 + (col - 1792), s + bias[TU+col]); \
          else gstf(pre + b*TU + col, s + bias[col]); \
        }
      __syncthreads(); STORE4(accW[0],accW[1],accW[2],accW[3]); __syncthreads();
      if (zr){ REDOUT(0, 0) } else { REDOUT(0, 1) }
      __syncthreads(); STORE4(accW[4],accW[5],accW[6],accW[7]); __syncthreads();
      if (zr){ REDOUT(4, 0) } else { REDOUT(4, 1) }
      if (!zr){
        __syncthreads(); STORE4(accX[0],accX[1],accX[2],accX[3]); __syncthreads();
        REDOUT(0, 2)
        __syncthreads(); STORE4(accX[4],accX[5],accX[6],accX[7]); __syncthreads();
        REDOUT(4, 2)
      }
      __syncthreads();
      if (tid==0) arrive(Fhv);

      // ---- gates (blocks 76..83): coarse-path GRU gates -> h0c (first 448 of h0) ----
      if (bk >= 76){
        if (tid==0){ spin_until(Fhv, 84u*(uint32_t)(t+1)); spin_until(Ffv, 8u*(uint32_t)t); }
        __syncthreads();
        if (tid < 448){
          const int b = tid/56, u = (bk-76)*56 + (tid - (tid/56)*56);
          const float fv = gldf(fvsB + ((t+1)&1)*8 + b);
          float az = gldf(pre + b*TU + u)        + fv*Wk[(size_t)81*TU + u];
          float ar = gldf(pre + b*TU + 896 + u)  + fv*Wk[(size_t)81*TU + 896 + u];
          float ax = gldf(pre + b*TU + 1792 + u) + fv*Wk[(size_t)81*TU + 1792 + u];
          float ih = gldf(ihb + b*896 + u);
          float hold = gldf(hgl + (t&1)*7168 + b*896 + u);
          float z = sig_f(az), r = sig_f(ar);
          float hh = tanh_f(ax + r*ih);
          gstf(h0c + b*HU + u, z*hold + (1.0f - z)*hh);
        }
        __syncthreads();
        if (tid==0) arrive(Fg);
      }

      // ---- h1c (blocks 0..55): relu(h0·W1c+b1c), 8 cols each ----
      if (bk < 56){
        if (tid==0) spin_until(Fg, 8u*(uint32_t)(t+1));
        __syncthreads();
        float* h0s = (float*)smem;
        float (*red2)[8] = (float(*)[8])(smem + 16384);
        for (int i=tid;i<3584;i+=NTH) h0s[i] = gldf(h0c + i);
        __syncthreads();
        const int c2 = tid&1, b1 = (tid>>1)&7, ks1 = tid>>4;  // ks1 0..31
        const int colb = bk*8 + c2*4;
        const int i0 = ks1*14;
        float4 a = make_float4(0,0,0,0);
        #pragma unroll
        for (int i=0;i<14;++i){
          const float4 w = *(const float4*)(W1c + (size_t)(i0+i)*HU + colb);
          fma4(a, w, h0s[b1*HU + i0+i]);
        }
        *(float4*)&red2[tid][0] = a;
        __syncthreads();
        if (tid < 64){
          const int ci = tid&7, b = tid>>3;
          float s = 0.f;
          #pragma unroll
          for (int q=0;q<32;++q) s += red2[q*16 + b*2 + (ci>>2)][ci&3];
          const int col = bk*8 + ci;
          gstf(hcbC + b*HU + col, fmaxf(s + b1c[col], 0.0f));
        }
        __syncthreads();
        if (tid==0) arrive(F1c);
      } else if (bk < 72){
        // ---- h2c (blocks 56..71): logits = y1·W2c+b2c, 16 cols each ----
        if (tid==0) spin_until(F1c, 56u*(uint32_t)(t+1));
        __syncthreads();
        float* shs = (float*)smem;
        float (*red3)[8] = (float(*)[8])(smem + 16384);
        for (int i=tid;i<3584;i+=NTH) shs[i] = gldf(hcbC + i);
        __syncthreads();
        const int c4b = tid&3, b1 = (tid>>2)&7, ks1 = tid>>5;  // ks1 0..15
        const int colb = (bk-56)*16 + c4b*4;
        const int i0 = ks1*28;
        float4 a = make_float4(0,0,0,0);
        #pragma unroll
        for (int i=0;i<28;++i){
          const float4 w = *(const float4*)(W2c + (size_t)(i0+i)*CC + colb);
          fma4(a, w, shs[b1*HU + i0+i]);
        }
        *(float4*)&red3[tid][0] = a;
        __syncthreads();
        if (tid < 128){
          const int ci = tid&15, b = tid>>4;
          float s = 0.f;
          #pragma unroll
          for (int q=0;q<16;++q) s += red3[q*32 + b*4 + (ci>>2)][ci&3];
          const int col = (bk-56)*16 + ci;
          gstf(lgtC + b*CC + col, s + b2c[col]);
        }
        __syncthreads();
        if (tid==0) arrive(F2c);
      }

      // ---- sample_c + fine gates (blocks 0..7, b = bk) ----
      if (bk < 8){
        if (tid==0) spin_until(F2c, 16u*(uint32_t)(t+1));
        __syncthreads();
        int nc = do_sample(smem, tid, lgtC, bk, kc[2*t], kc[2*t+1]);
        float* sv = (float*)(smem + 2048);
        if (tid==0){
          gsti(nci + bk, nc);
          float val = (float)nc/255.0f*2.0f - 1.0f;
          gstf(ncvB + (t&1)*8 + bk, val);
          *sv = val;
        }
        __syncthreads();
        const float ncv = *sv;
        const float fv = gldf(fvsB + ((t+1)&1)*8 + bk);
        const int hsO = (t&1)*7168, hsN = ((t+1)&1)*7168;
        #pragma unroll
        for (int rep=0;rep<2;++rep){
          int u = tid + rep*512;
          if (u < 896){
            float az = gldf(pre + bk*TU + u)        + fv*Wk[(size_t)81*TU + u]        + ncv*Wk[(size_t)82*TU + u];
            float ar = gldf(pre + bk*TU + 896 + u)  + fv*Wk[(size_t)81*TU + 896 + u]  + ncv*Wk[(size_t)82*TU + 896 + u];
            float ax = gldf(pre + bk*TU + 1792 + u) + fv*Wk[(size_t)81*TU + 1792 + u] + ncv*Wk[(size_t)82*TU + 1792 + u];
            float ih = gldf(ihb + bk*896 + u);
            float hold = gldf(hgl + hsO + bk*896 + u);
            float z = sig_f(az), r = sig_f(ar);
            float hh = tanh_f(ax + r*ih);
            gstf(hgl + hsN + bk*896 + u, z*hold + (1.0f - z)*hh);
          }
        }
        __syncthreads();
        if (tid==0) arrive(Fh1);
      }
    }
  } else if (bk < 140){
    // ======== h1f (56 blocks, 8 cols each): relu(h1[:,448:]·W1f+b1f) ========
    const int jb = bk - 84;
    for (int t=0; t<TT; ++t){
      if (tid==0) spin_until(Fh1, 8u*(uint32_t)(t+1));
      __syncthreads();
      float* hfs = (float*)smem;
      float (*red2)[8] = (float(*)[8])(smem + 16384);
      const int hsN = ((t+1)&1)*7168;
      for (int i=tid;i<3584;i+=NTH){ int b = i/HU, ii = i - b*HU; hfs[i] = gldf(hgl + hsN + b*U + HU + ii); }
      __syncthreads();
      const int c2 = tid&1, b1 = (tid>>1)&7, ks1 = tid>>4;
      const int colb = jb*8 + c2*4;
      const int i0 = ks1*14;
      float4 a = make_float4(0,0,0,0);
      #pragma unroll
      for (int i=0;i<14;++i){
        const float4 w = *(const float4*)(W1f + (size_t)(i0+i)*HU + colb);
        fma4(a, w, hfs[b1*HU + i0+i]);
      }
      *(float4*)&red2[tid][0] = a;
      __syncthreads();
      if (tid < 64){
        const int ci = tid&7, b = tid>>3;
        float s = 0.f;
        #pragma unroll
        for (int q=0;q<32;++q) s += red2[q*16 + b*2 + (ci>>2)][ci&3];
        const int col = jb*8 + ci;
        gstf(hcbF + b*HU + col, fmaxf(s + b1f[col], 0.0f));
      }
      __syncthreads();
      if (tid==0) arrive(F1f);
    }
  } else if (bk < 156){
    // ======== h2f (16 blocks, 16 cols each) ========
    const int jb = bk - 140;
    for (int t=0; t<TT; ++t){
      if (tid==0) spin_until(F1f, 56u*(uint32_t)(t+1));
      __syncthreads();
      float* shs = (float*)smem;
      float (*red3)[8] = (float(*)[8])(smem + 16384);
      for (int i=tid;i<3584;i+=NTH) shs[i] = gldf(hcbF + i);
      __syncthreads();
      const int c4b = tid&3, b1 = (tid>>2)&7, ks1 = tid>>5;
      const int colb = jb*16 + c4b*4;
      const int i0 = ks1*28;
      float4 a = make_float4(0,0,0,0);
      #pragma unroll
      for (int i=0;i<28;++i){
        const float4 w = *(const float4*)(W2f + (size_t)(i0+i)*CC + colb);
        fma4(a, w, shs[b1*HU + i0+i]);
      }
      *(float4*)&red3[tid][0] = a;
      __syncthreads();
      if (tid < 128){
        const int ci = tid&15, b = tid>>4;
        float s = 0.f;
        #pragma unroll
        for (int q=0;q<16;++q) s += red3[q*32 + b*4 + (ci>>2)][ci&3];
        const int col = jb*16 + ci;
        gstf(lgtF + b*CC + col, s + b2f[col]);
      }
      __syncthreads();
      if (tid==0) arrive(F2f);
    }
  } else {
    // ======== sample_f (8 blocks, b = bk-156) ========
    const int b = bk - 156;
    for (int t=0; t<TT; ++t){
      if (tid==0) spin_until(F2f, 16u*(uint32_t)(t+1));
      __syncthreads();
      int nf = do_sample(smem, tid, lgtF, b, kf[2*t], kf[2*t+1]);
      if (tid==0){
        float nff = (float)nf;
        gstf(fvsB + (t&1)*8 + b, nff/255.0f*2.0f - 1.0f);
        int nc = gldi(nci + b);
        out[(size_t)b*TT + t] = ((float)nc*256.0f + nff)/32767.5f - 1.0f;
        arrive(Ffv);
      }
    }
  }
}

extern "C" void kernel_launch(void* const* d_in, const int* in_sizes, int n_in,
                              void* d_out, int out_size, void* d_ws, size_t ws_size,
                              hipStream_t stream) {
  const float* mels = (const float*)d_in[0];
  const float* Wk   = (const float*)d_in[1];
  const float* Wr   = (const float*)d_in[2];
  const float* bias = (const float*)d_in[3];
  const float* W1c  = (const float*)d_in[4];
  const float* b1c  = (const float*)d_in[5];
  const float* W2c  = (const float*)d_in[6];
  const float* b2c  = (const float*)d_in[7];
  const float* W1f  = (const float*)d_in[8];
  const float* b1f  = (const float*)d_in[9];
  const float* W2f  = (const float*)d_in[10];
  const float* b2f  = (const float*)d_in[11];
  float* out = (float*)d_out;
  char* wsb = (char*)d_ws;

  uint32_t* kc = (uint32_t*)(wsb + 1024);
  uint32_t* kf = (uint32_t*)(wsb + 5120);

  hipMemsetAsync(d_ws, 0, 240896, stream);
  k_keys<<<2,256,0,stream>>>(kc, kf);

  void* args[] = { (void*)&mels, (void*)&Wk, (void*)&Wr, (void*)&bias,
                   (void*)&W1c, (void*)&b1c, (void*)&W2c, (void*)&b2c,
                   (void*)&W1f, (void*)&b1f, (void*)&W2f, (void*)&b2f,
                   (void*)&out, (void*)&wsb };
  hipLaunchCooperativeKernel((const void*)wavernn_persist, dim3(NBLK), dim3(NTH),
                             args, 0, stream);
}

// Round 5
// 20087.334 us; speedup vs baseline: 2.4568x; 1.2567x over previous
//
#include <hip/hip_runtime.h>
#include <cstdint>
#include <math.h>

#define U 896
#define HU 448
#define TU 2688
#define BB 8
#define TT 512
#define MM 80
#define CC 256
#define NTH 512
#define NBLK 188

// ---------------- Threefry-2x32 (JAX partitionable) ----------------
__device__ __forceinline__ uint32_t rotl32(uint32_t v, int r){ return (v<<r)|(v>>(32-r)); }

__device__ void threefry(uint32_t k0, uint32_t k1, uint32_t x0, uint32_t x1,
                         uint32_t* o0, uint32_t* o1){
  uint32_t k2 = k0 ^ k1 ^ 0x1BD11BDAu;
  x0 += k0; x1 += k1;
  x0+=x1; x1=rotl32(x1,13); x1^=x0;
  x0+=x1; x1=rotl32(x1,15); x1^=x0;
  x0+=x1; x1=rotl32(x1,26); x1^=x0;
  x0+=x1; x1=rotl32(x1, 6); x1^=x0;
  x0+=k1; x1+=k2+1u;
  x0+=x1; x1=rotl32(x1,17); x1^=x0;
  x0+=x1; x1=rotl32(x1,29); x1^=x0;
  x0+=x1; x1=rotl32(x1,16); x1^=x0;
  x0+=x1; x1=rotl32(x1,24); x1^=x0;
  x0+=k2; x1+=k0+2u;
  x0+=x1; x1=rotl32(x1,13); x1^=x0;
  x0+=x1; x1=rotl32(x1,15); x1^=x0;
  x0+=x1; x1=rotl32(x1,26); x1^=x0;
  x0+=x1; x1=rotl32(x1, 6); x1^=x0;
  x0+=k0; x1+=k1+3u;
  x0+=x1; x1=rotl32(x1,17); x1^=x0;
  x0+=x1; x1=rotl32(x1,29); x1^=x0;
  x0+=x1; x1=rotl32(x1,16); x1^=x0;
  x0+=x1; x1=rotl32(x1,24); x1^=x0;
  x0+=k1; x1+=k2+4u;
  x0+=x1; x1=rotl32(x1,13); x1^=x0;
  x0+=x1; x1=rotl32(x1,15); x1^=x0;
  x0+=x1; x1=rotl32(x1,26); x1^=x0;
  x0+=x1; x1=rotl32(x1, 6); x1^=x0;
  x0+=k2; x1+=k0+5u;
  *o0 = x0; *o1 = x1;
}

__device__ float gumbel_from(uint32_t ka, uint32_t kb, uint32_t e){
  uint32_t o0, o1;
  threefry(ka, kb, 0u, e, &o0, &o1);
  uint32_t bits = o0 ^ o1;
  uint32_t m = bits >> 9;
  float u = (m == 0u) ? 1.17549435e-38f
                      : (__uint_as_float(m | 0x3f800000u) - 1.0f);
  float l1 = (float)log((double)u);
  float l2 = (float)log((double)(-l1));
  return -l2;
}

__device__ __forceinline__ float sig_f(float x){
  return (float)(0.5 + 0.5*tanh(0.5*(double)x));
}
__device__ __forceinline__ float tanh_f(float x){ return (float)tanh((double)x); }

// ---------------- coherent (agent-scope) access ----------------
__device__ __forceinline__ float gldf(const float* p){
  return __hip_atomic_load(p, __ATOMIC_RELAXED, __HIP_MEMORY_SCOPE_AGENT);
}
__device__ __forceinline__ void gstf(float* p, float v){
  __hip_atomic_store(p, v, __ATOMIC_RELAXED, __HIP_MEMORY_SCOPE_AGENT);
}
__device__ __forceinline__ int gldi(const int* p){
  return __hip_atomic_load(p, __ATOMIC_RELAXED, __HIP_MEMORY_SCOPE_AGENT);
}
__device__ __forceinline__ void gsti(int* p, int v){
  __hip_atomic_store(p, v, __ATOMIC_RELAXED, __HIP_MEMORY_SCOPE_AGENT);
}

// per-producer slots, 128B apart (32 u32)
__device__ __forceinline__ void wait_slots(const uint32_t* slots, int n, uint32_t tgt, int tid){
  if (tid < n){
    const uint32_t* p = slots + (size_t)tid*32;
    int it = 0;
    while (__hip_atomic_load(p, __ATOMIC_RELAXED, __HIP_MEMORY_SCOPE_AGENT) < tgt){
      __builtin_amdgcn_s_sleep(1);
      if (++it > (1<<22)) break;
    }
  }
  __syncthreads();
}
__device__ __forceinline__ void publish_slot(uint32_t* slot, uint32_t v, int tid){
  __syncthreads();
  if (tid == 0)
    __hip_atomic_store(slot, v, __ATOMIC_RELEASE, __HIP_MEMORY_SCOPE_AGENT);
}

__device__ __forceinline__ void fma4(float4& a, const float4& w, float h){
  a.x += w.x*h; a.y += w.y*h; a.z += w.z*h; a.w += w.w*h;
}

// butterfly-sum 8 float4 accumulators over lane bits 3..5 (ks within wave)
__device__ __forceinline__ void bf8(float4* a){
  #pragma unroll
  for (int d=8; d<64; d<<=1){
    #pragma unroll
    for (int b=0;b<8;++b){
      a[b].x += __shfl_xor(a[b].x, d);
      a[b].y += __shfl_xor(a[b].y, d);
      a[b].z += __shfl_xor(a[b].z, d);
      a[b].w += __shfl_xor(a[b].w, d);
    }
  }
}

// ---------------- K0: per-step keys ----------------
__global__ __launch_bounds__(256) void k_keys(uint32_t* __restrict__ kc, uint32_t* __restrict__ kf){
  int t = blockIdx.x*256 + threadIdx.x;
  if (t >= TT) return;
  uint32_t ka, kb;
  threefry(0u, 42u, 0u, (uint32_t)t, &ka, &kb);
  uint32_t c0,c1,f0,f1;
  threefry(ka, kb, 0u, 0u, &c0, &c1);
  threefry(ka, kb, 0u, 1u, &f0, &f1);
  kc[2*t] = c0; kc[2*t+1] = c1;
  kf[2*t] = f0; kf[2*t+1] = f1;
}

// ws offsets
#define O_SH1   0
#define O_SH1HI 1024
#define O_SFV   2048
#define O_SG    3072
#define O_SY1C  6656
#define O_SLC   13824
#define O_SY1F  15872
#define O_SLF   23040
#define O_KC    25088
#define O_KF    29184
#define O_NCV   33280
#define O_FVS   33344
#define O_NCI   33408
#define O_PRE   33536
#define O_IHB   119552
#define O_HGL   148224
#define O_H0C   205568
#define O_Y1C   219904
#define O_Y1F   234240
#define O_LGTC  248576
#define O_LGTF  256768
#define WS_ZERO 264960

// ---------------- persistent kernel ----------------
__global__ __launch_bounds__(NTH, 2) void wavernn_persist(
    const float* __restrict__ mels, const float* __restrict__ Wk,
    const float* __restrict__ Wr,  const float* __restrict__ bias,
    const float* __restrict__ W1c, const float* __restrict__ b1c,
    const float* __restrict__ W2c, const float* __restrict__ b2c,
    const float* __restrict__ W1f, const float* __restrict__ b1f,
    const float* __restrict__ W2f, const float* __restrict__ b2f,
    float* __restrict__ out, char* __restrict__ ws)
{
  uint32_t* SH1   = (uint32_t*)(ws + O_SH1);
  uint32_t* SH1HI = (uint32_t*)(ws + O_SH1HI);
  uint32_t* SFV   = (uint32_t*)(ws + O_SFV);
  uint32_t* SG    = (uint32_t*)(ws + O_SG);
  uint32_t* SY1C  = (uint32_t*)(ws + O_SY1C);
  uint32_t* SLC   = (uint32_t*)(ws + O_SLC);
  uint32_t* SY1F  = (uint32_t*)(ws + O_SY1F);
  uint32_t* SLF   = (uint32_t*)(ws + O_SLF);
  const uint32_t* kc = (const uint32_t*)(ws + O_KC);
  const uint32_t* kf = (const uint32_t*)(ws + O_KF);
  float* ncvB = (float*)(ws + O_NCV);   // [2][8]
  float* fvsB = (float*)(ws + O_FVS);   // [2][8]
  int*   nci  = (int*)  (ws + O_NCI);
  float* pre  = (float*)(ws + O_PRE);   // [8][2688]
  float* ihb  = (float*)(ws + O_IHB);   // [8][896]
  float* hgl  = (float*)(ws + O_HGL);   // [2][8*896]
  float* h0c  = (float*)(ws + O_H0C);   // [8][448]
  float* y1c  = (float*)(ws + O_Y1C);   // [8][448]
  float* y1f  = (float*)(ws + O_Y1F);   // [8][448]
  float* lgtC = (float*)(ws + O_LGTC);  // [8][256]
  float* lgtF = (float*)(ws + O_LGTF);  // [8][256]

  __shared__ __align__(16) char smem[46080];
  const int bk = blockIdx.x, tid = threadIdx.x;

  if (bk < 28){
    // ================= GEMM + gates-epilogue =================
    const int c4i = tid & 7, ks = tid >> 3;     // 8 f4-cols x 64 ksegs
    const int k0 = ks*14;
    const int lane = tid & 63, wv = tid >> 6;
    const int U0 = bk*32;
    const int cb0 = U0 + c4i*4;
    float* hlf   = (float*)smem;                 // [8][1024] = 32KB
    float* wredf = (float*)(smem + 32768);       // [8 waves][8 c4i(36 stride)] = 9216B
    float* gbuf  = (float*)(smem + 41984);       // [8][32][4] = 4KB
    const int xk = 896 + ks*2;
    const int r0 = ((xk   < 978) ? xk   : 978) - 896;
    const int r1 = ((xk+1 < 978) ? xk+1 : 978) - 896;

    for (int t=0; t<TT; ++t){
      wait_slots(SH1, 8, (uint32_t)t, tid);
      const int hs = (t&1)*7168;
      for (int i=tid;i<8192;i+=NTH){
        const int b = i>>10, k = i&1023;
        float v;
        if (k < 896)      v = gldf(hgl + hs + b*896 + k);
        else if (k < 976) v = mels[((size_t)b*TT + t)*MM + (k-896)];
        else if (k == 976)v = gldf(ncvB + ((t+1)&1)*8 + b);
        else              v = 0.f;
        hlf[i] = v;
      }
      __syncthreads();

      for (int g=0; g<3; ++g){
        const int cbg = g*896 + cb0;
        float4 aW[8], aX[8];
        #pragma unroll
        for (int b=0;b<8;++b){ aW[b]=make_float4(0,0,0,0); aX[b]=make_float4(0,0,0,0); }
        #pragma unroll 2
        for (int j=0;j<14;++j){
          const float4 w = *(const float4*)(Wr + (size_t)(k0+j)*TU + cbg);
          #pragma unroll
          for (int b=0;b<8;++b) fma4(aW[b], w, hlf[b*1024 + k0 + j]);
        }
        {
          const float4 w0 = *(const float4*)(Wk + (size_t)r0*TU + cbg);
          const float4 w1 = *(const float4*)(Wk + (size_t)r1*TU + cbg);
          #pragma unroll
          for (int b=0;b<8;++b){
            fma4(aX[b], w0, hlf[b*1024 + 896 + ks*2]);
            fma4(aX[b], w1, hlf[b*1024 + 897 + ks*2]);
          }
        }
        if (g < 2){
          #pragma unroll
          for (int b=0;b<8;++b){
            aW[b].x += aX[b].x; aW[b].y += aX[b].y;
            aW[b].z += aX[b].z; aW[b].w += aX[b].w;
          }
          bf8(aW);
          if (lane < 8){
            float* dst = wredf + wv*288 + lane*36;
            #pragma unroll
            for (int b=0;b<8;++b) *(float4*)(dst + b*4) = aW[b];
          }
          __syncthreads();
          if (tid < 256){
            const int b = tid>>5, ci = tid&31;
            float s = 0.f;
            #pragma unroll
            for (int w=0; w<8; ++w) s += wredf[w*288 + (ci>>2)*36 + b*4 + (ci&3)];
            const int col = g*896 + U0 + ci;
            const float val = s + bias[col] + bias[TU + col];
            gstf(pre + b*TU + col, val);
            gbuf[(b*32 + ci)*4 + g] = val;
          }
          __syncthreads();
        } else {
          bf8(aW);
          if (lane < 8){
            float* dst = wredf + wv*288 + lane*36;
            #pragma unroll
            for (int b=0;b<8;++b) *(float4*)(dst + b*4) = aW[b];
          }
          __syncthreads();
          if (tid < 256){
            const int b = tid>>5, ci = tid&31;
            float s = 0.f;
            #pragma unroll
            for (int w=0; w<8; ++w) s += wredf[w*288 + (ci>>2)*36 + b*4 + (ci&3)];
            const int u = U0 + ci;
            const float val = s + bias[TU + 1792 + u];
            gstf(ihb + b*896 + u, val);
            gbuf[(b*32 + ci)*4 + 3] = val;
          }
          __syncthreads();
          bf8(aX);
          if (lane < 8){
            float* dst = wredf + wv*288 + lane*36;
            #pragma unroll
            for (int b=0;b<8;++b) *(float4*)(dst + b*4) = aX[b];
          }
          __syncthreads();
          if (tid < 256){
            const int b = tid>>5, ci = tid&31;
            float s = 0.f;
            #pragma unroll
            for (int w=0; w<8; ++w) s += wredf[w*288 + (ci>>2)*36 + b*4 + (ci&3)];
            const int u = U0 + ci;
            const float val = s + bias[1792 + u];
            gstf(pre + b*TU + 1792 + u, val);
            gbuf[(b*32 + ci)*4 + 2] = val;
          }
          __syncthreads();
        }
      }

      if (bk < 14){
        // coarse gates epilogue: needs fv(t-1)
        wait_slots(SFV, 8, (uint32_t)t, tid);
        if (tid < 256){
          const int b = tid>>5, ub = tid&31, u = U0 + ub;
          const float fv = gldf(fvsB + ((t+1)&1)*8 + b);
          const float* gb = gbuf + (b*32 + ub)*4;
          const float az = gb[0] + fv*Wk[(size_t)81*TU + u];
          const float ar = gb[1] + fv*Wk[(size_t)81*TU + 896 + u];
          const float ax = gb[2] + fv*Wk[(size_t)81*TU + 1792 + u];
          const float z = sig_f(az), r = sig_f(ar);
          const float hh = tanh_f(ax + r*gb[3]);
          gstf(h0c + b*HU + u, z*hlf[b*1024 + u] + (1.0f - z)*hh);
        }
      }
      publish_slot(SG + bk*32, (uint32_t)(t+1), tid);
    }
  } else if (bk < 84){
    // ================= h1c: relu(h0c @ W1c + b1c), 8 cols =================
    const int j = bk - 28;
    float* h0s = (float*)smem;
    float (*red2)[8] = (float(*)[8])(smem + 16384);
    const int c2 = tid&1, b1 = (tid>>1)&7, ks1 = tid>>4;
    const int colb = j*8 + c2*4, i0 = ks1*14;
    for (int t=0; t<TT; ++t){
      wait_slots(SG, 14, (uint32_t)(t+1), tid);
      for (int i=tid;i<3584;i+=NTH) h0s[i] = gldf(h0c + i);
      __syncthreads();
      float4 a = make_float4(0,0,0,0);
      #pragma unroll
      for (int i=0;i<14;++i){
        const float4 w = *(const float4*)(W1c + (size_t)(i0+i)*HU + colb);
        fma4(a, w, h0s[b1*HU + i0+i]);
      }
      *(float4*)&red2[tid][0] = a;
      __syncthreads();
      if (tid < 64){
        const int ci = tid&7, b = tid>>3;
        float s = 0.f;
        #pragma unroll
        for (int q=0;q<32;++q) s += red2[q*16 + b*2 + (ci>>2)][ci&3];
        const int col = j*8 + ci;
        gstf(y1c + b*HU + col, fmaxf(s + b1c[col], 0.0f));
      }
      publish_slot(SY1C + j*32, (uint32_t)(t+1), tid);
    }
  } else if (bk < 100){
    // ================= h2c: logits = y1c @ W2c + b2c, 16 cols =================
    const int j = bk - 84;
    float* shs = (float*)smem;
    float (*red3)[8] = (float(*)[8])(smem + 16384);
    const int c4b = tid&3, b1 = (tid>>2)&7, ks1 = tid>>5;
    const int colb = j*16 + c4b*4, i0 = ks1*28;
    for (int t=0; t<TT; ++t){
      wait_slots(SY1C, 56, (uint32_t)(t+1), tid);
      for (int i=tid;i<3584;i+=NTH) shs[i] = gldf(y1c + i);
      __syncthreads();
      float4 a = make_float4(0,0,0,0);
      #pragma unroll
      for (int i=0;i<28;++i){
        const float4 w = *(const float4*)(W2c + (size_t)(i0+i)*CC + colb);
        fma4(a, w, shs[b1*HU + i0+i]);
      }
      *(float4*)&red3[tid][0] = a;
      __syncthreads();
      if (tid < 128){
        const int ci = tid&15, b = tid>>4;
        float s = 0.f;
        #pragma unroll
        for (int q=0;q<16;++q) s += red3[q*32 + b*4 + (ci>>2)][ci&3];
        const int col = j*16 + ci;
        gstf(lgtC + b*CC + col, s + b2c[col]);
      }
      publish_slot(SLC + j*32, (uint32_t)(t+1), tid);
    }
  } else if (bk < 108){
    // ================= sample_c + fine gates (b = bk-100) =================
    const int b = bk - 100;
    float* sredf = (float*)smem;
    int*   sredi = (int*)(smem + 64);
    for (int t=0; t<TT; ++t){
      const float gmb = (tid<256) ? gumbel_from(kc[2*t], kc[2*t+1], (uint32_t)(b*CC + tid)) : 0.f;
      wait_slots(SLC, 16, (uint32_t)(t+1), tid);
      wait_slots(SG, 28, (uint32_t)(t+1), tid);
      const float logit = (tid<256) ? gldf(lgtC + b*CC + tid) : -3.402823466e38f;
      float m = logit;
      #pragma unroll
      for (int d=1; d<64; d<<=1) m = fmaxf(m, __shfl_xor(m, d));
      if ((tid&63)==0) sredf[tid>>6] = m;
      __syncthreads();
      const float mx = fmaxf(fmaxf(sredf[0],sredf[1]), fmaxf(sredf[2],sredf[3]));
      __syncthreads();
      const float e = (tid<256) ? (float)exp((double)(logit - mx)) : 0.f;
      float ss = e;
      #pragma unroll
      for (int d=1; d<64; d<<=1) ss += __shfl_xor(ss, d);
      if ((tid&63)==0) sredf[tid>>6] = ss;
      __syncthreads();
      const float sum = (sredf[0]+sredf[1])+(sredf[2]+sredf[3]);
      __syncthreads();
      float v = (tid<256) ? (e/sum + gmb) : -3.402823466e38f;
      int bi = (tid<256) ? tid : (1<<30);
      #pragma unroll
      for (int d=1; d<64; d<<=1){
        const float ov = __shfl_xor(v, d);
        const int   oi = __shfl_xor(bi, d);
        if (ov > v || (ov == v && oi < bi)){ v = ov; bi = oi; }
      }
      if ((tid&63)==0){ sredf[tid>>6] = v; sredi[tid>>6] = bi; }
      __syncthreads();
      float bv = sredf[0]; int nc = sredi[0];
      #pragma unroll
      for (int w=1; w<4; ++w){
        if (sredf[w] > bv || (sredf[w] == bv && sredi[w] < nc)){ bv = sredf[w]; nc = sredi[w]; }
      }
      if (tid==0){
        gsti(nci + b, nc);
        gstf(ncvB + (t&1)*8 + b, (float)nc/255.0f*2.0f - 1.0f);
      }
      const float ncv = (float)nc/255.0f*2.0f - 1.0f;
      const float fv = gldf(fvsB + ((t+1)&1)*8 + b);
      const int hsO = (t&1)*7168, hsN = ((t+1)&1)*7168;
      if (tid < 448){
        const int u = 448 + tid;
        const float az = gldf(pre + b*TU + u)        + fv*Wk[(size_t)81*TU + u]        + ncv*Wk[(size_t)82*TU + u];
        const float ar = gldf(pre + b*TU + 896 + u)  + fv*Wk[(size_t)81*TU + 896 + u]  + ncv*Wk[(size_t)82*TU + 896 + u];
        const float ax = gldf(pre + b*TU + 1792 + u) + fv*Wk[(size_t)81*TU + 1792 + u] + ncv*Wk[(size_t)82*TU + 1792 + u];
        const float ih = gldf(ihb + b*896 + u);
        const float z = sig_f(az), r = sig_f(ar);
        const float hh = tanh_f(ax + r*ih);
        gstf(hgl + hsN + b*896 + u, z*gldf(hgl + hsO + b*896 + u) + (1.0f - z)*hh);
      }
      publish_slot(SH1HI + b*32, (uint32_t)(t+1), tid);
      if (tid < 448){
        const int u = tid;
        const float az = gldf(pre + b*TU + u)        + fv*Wk[(size_t)81*TU + u]        + ncv*Wk[(size_t)82*TU + u];
        const float ar = gldf(pre + b*TU + 896 + u)  + fv*Wk[(size_t)81*TU + 896 + u]  + ncv*Wk[(size_t)82*TU + 896 + u];
        const float ax = gldf(pre + b*TU + 1792 + u) + fv*Wk[(size_t)81*TU + 1792 + u] + ncv*Wk[(size_t)82*TU + 1792 + u];
        const float ih = gldf(ihb + b*896 + u);
        const float z = sig_f(az), r = sig_f(ar);
        const float hh = tanh_f(ax + r*ih);
        gstf(hgl + hsN + b*896 + u, z*gldf(hgl + hsO + b*896 + u) + (1.0f - z)*hh);
      }
      publish_slot(SH1 + b*32, (uint32_t)(t+1), tid);
    }
  } else if (bk < 164){
    // ================= h1f: relu(h1[:,448:] @ W1f + b1f), 8 cols =================
    const int j = bk - 108;
    float* hfs = (float*)smem;
    float (*red2)[8] = (float(*)[8])(smem + 16384);
    const int c2 = tid&1, b1 = (tid>>1)&7, ks1 = tid>>4;
    const int colb = j*8 + c2*4, i0 = ks1*14;
    for (int t=0; t<TT; ++t){
      wait_slots(SH1HI, 8, (uint32_t)(t+1), tid);
      const int hsN = ((t+1)&1)*7168;
      for (int i=tid;i<3584;i+=NTH){
        const int b = i/HU, ii = i - b*HU;
        hfs[i] = gldf(hgl + hsN + b*U + HU + ii);
      }
      __syncthreads();
      float4 a = make_float4(0,0,0,0);
      #pragma unroll
      for (int i=0;i<14;++i){
        const float4 w = *(const float4*)(W1f + (size_t)(i0+i)*HU + colb);
        fma4(a, w, hfs[b1*HU + i0+i]);
      }
      *(float4*)&red2[tid][0] = a;
      __syncthreads();
      if (tid < 64){
        const int ci = tid&7, b = tid>>3;
        float s = 0.f;
        #pragma unroll
        for (int q=0;q<32;++q) s += red2[q*16 + b*2 + (ci>>2)][ci&3];
        const int col = j*8 + ci;
        gstf(y1f + b*HU + col, fmaxf(s + b1f[col], 0.0f));
      }
      publish_slot(SY1F + j*32, (uint32_t)(t+1), tid);
    }
  } else if (bk < 180){
    // ================= h2f =================
    const int j = bk - 164;
    float* shs = (float*)smem;
    float (*red3)[8] = (float(*)[8])(smem + 16384);
    const int c4b = tid&3, b1 = (tid>>2)&7, ks1 = tid>>5;
    const int colb = j*16 + c4b*4, i0 = ks1*28;
    for (int t=0; t<TT; ++t){
      wait_slots(SY1F, 56, (uint32_t)(t+1), tid);
      for (int i=tid;i<3584;i+=NTH) shs[i] = gldf(y1f + i);
      __syncthreads();
      float4 a = make_float4(0,0,0,0);
      #pragma unroll
      for (int i=0;i<28;++i){
        const float4 w = *(const float4*)(W2f + (size_t)(i0+i)*CC + colb);
        fma4(a, w, shs[b1*HU + i0+i]);
      }
      *(float4*)&red3[tid][0] = a;
      __syncthreads();
      if (tid < 128){
        const int ci = tid&15, b = tid>>4;
        float s = 0.f;
        #pragma unroll
        for (int q=0;q<16;++q) s += red3[q*32 + b*4 + (ci>>2)][ci&3];
        const int col = j*16 + ci;
        gstf(lgtF + b*CC + col, s + b2f[col]);
      }
      publish_slot(SLF + j*32, (uint32_t)(t+1), tid);
    }
  } else {
    // ================= sample_f (b = bk-180) =================
    const int b = bk - 180;
    float* sredf = (float*)smem;
    int*   sredi = (int*)(smem + 64);
    for (int t=0; t<TT; ++t){
      const float gmb = (tid<256) ? gumbel_from(kf[2*t], kf[2*t+1], (uint32_t)(b*CC + tid)) : 0.f;
      wait_slots(SLF, 16, (uint32_t)(t+1), tid);
      const float logit = (tid<256) ? gldf(lgtF + b*CC + tid) : -3.402823466e38f;
      float m = logit;
      #pragma unroll
      for (int d=1; d<64; d<<=1) m = fmaxf(m, __shfl_xor(m, d));
      if ((tid&63)==0) sredf[tid>>6] = m;
      __syncthreads();
      const float mx = fmaxf(fmaxf(sredf[0],sredf[1]), fmaxf(sredf[2],sredf[3]));
      __syncthreads();
      const float e = (tid<256) ? (float)exp((double)(logit - mx)) : 0.f;
      float ss = e;
      #pragma unroll
      for (int d=1; d<64; d<<=1) ss += __shfl_xor(ss, d);
      if ((tid&63)==0) sredf[tid>>6] = ss;
      __syncthreads();
      const float sum = (sredf[0]+sredf[1])+(sredf[2]+sredf[3]);
      __syncthreads();
      float v = (tid<256) ? (e/sum + gmb) : -3.402823466e38f;
      int bi = (tid<256) ? tid : (1<<30);
      #pragma unroll
      for (int d=1; d<64; d<<=1){
        const float ov = __shfl_xor(v, d);
        const int   oi = __shfl_xor(bi, d);
        if (ov > v || (ov == v && oi < bi)){ v = ov; bi = oi; }
      }
      if ((tid&63)==0){ sredf[tid>>6] = v; sredi[tid>>6] = bi; }
      __syncthreads();
      float bv = sredf[0]; int nf = sredi[0];
      #pragma unroll
      for (int w=1; w<4; ++w){
        if (sredf[w] > bv || (sredf[w] == bv && sredi[w] < nf)){ bv = sredf[w]; nf = sredi[w]; }
      }
      if (tid==0){
        gstf(fvsB + (t&1)*8 + b, (float)nf/255.0f*2.0f - 1.0f);
        const int nc = gldi(nci + b);
        out[(size_t)b*TT + t] = ((float)nc*256.0f + (float)nf)/32767.5f - 1.0f;
      }
      publish_slot(SFV + b*32, (uint32_t)(t+1), tid);
    }
  }
}

extern "C" void kernel_launch(void* const* d_in, const int* in_sizes, int n_in,
                              void* d_out, int out_size, void* d_ws, size_t ws_size,
                              hipStream_t stream) {
  const float* mels = (const float*)d_in[0];
  const float* Wk   = (const float*)d_in[1];
  const float* Wr   = (const float*)d_in[2];
  const float* bias = (const float*)d_in[3];
  const float* W1c  = (const float*)d_in[4];
  const float* b1c  = (const float*)d_in[5];
  const float* W2c  = (const float*)d_in[6];
  const float* b2c  = (const float*)d_in[7];
  const float* W1f  = (const float*)d_in[8];
  const float* b1f  = (const float*)d_in[9];
  const float* W2f  = (const float*)d_in[10];
  const float* b2f  = (const float*)d_in[11];
  float* out = (float*)d_out;
  char* wsb = (char*)d_ws;

  uint32_t* kc = (uint32_t*)(wsb + O_KC);
  uint32_t* kf = (uint32_t*)(wsb + O_KF);

  hipMemsetAsync(d_ws, 0, WS_ZERO, stream);
  k_keys<<<2,256,0,stream>>>(kc, kf);

  void* args[] = { (void*)&mels, (void*)&Wk, (void*)&Wr, (void*)&bias,
                   (void*)&W1c, (void*)&b1c, (void*)&W2c, (void*)&b2c,
                   (void*)&W1f, (void*)&b1f, (void*)&W2f, (void*)&b2f,
                   (void*)&out, (void*)&wsb };
  hipLaunchCooperativeKernel((const void*)wavernn_persist, dim3(NBLK), dim3(NTH),
                             args, 0, stream);
}